// Round 7
// baseline (341.791 us; speedup 1.0000x reference)
//
#include <hip/hip_runtime.h>

#define NB 4
#define CIN 512
#define NPIX 4096
#define CQK 64
#define COUT 256
#define PPIX 4356   // 66*66 padded pixels

typedef __bf16 bh16;
typedef _Float16 fh16;
typedef __attribute__((ext_vector_type(8))) __bf16 bf16x8;
typedef __attribute__((ext_vector_type(8))) _Float16 f16x8;
typedef __attribute__((ext_vector_type(16))) float f32x16;

#define AS1 __attribute__((address_space(1)))
#define AS3 __attribute__((address_space(3)))

__device__ __forceinline__ void glds16(const void* g, void* l) {
  __builtin_amdgcn_global_load_lds((const AS1 unsigned int*)g, (AS3 unsigned int*)l, 16, 0, 0);
}

// ---------- transpose x [B][C][N] -> xTb [B][N][C] bf16 ----------
__global__ __launch_bounds__(256) void transpose_bf_k(const float* __restrict__ src,
                                                      bh16* __restrict__ dst,
                                                      int rows, int cols) {
  __shared__ float tile[32][33];
  const int b = blockIdx.z;
  const int c0 = blockIdx.x * 32;   // over cols (N)
  const int r0 = blockIdx.y * 32;   // over rows (C)
  const float* s = src + (size_t)b * rows * cols;
  bh16* d = dst + (size_t)b * rows * cols;
  const int tx = threadIdx.x, ty = threadIdx.y;  // 32 x 8
#pragma unroll
  for (int i = 0; i < 32; i += 8)
    tile[ty + i][tx] = s[(size_t)(r0 + ty + i) * cols + (c0 + tx)];
  __syncthreads();
#pragma unroll
  for (int i = 0; i < 32; i += 8)
    d[(size_t)(c0 + ty + i) * rows + (r0 + tx)] = (bh16)tile[tx][ty + i];
}

// ---------- cast weights to bf16: Wqk[128][512] = [wq;wk], wvb[512][512], bias128 ----------
__global__ __launch_bounds__(256) void wcast_k(const float* __restrict__ wq,
                                               const float* __restrict__ wk,
                                               const float* __restrict__ wv,
                                               const float* __restrict__ bq,
                                               const float* __restrict__ bk,
                                               bh16* __restrict__ Wqk,
                                               bh16* __restrict__ wvb,
                                               float* __restrict__ bias128) {
  const int idx = blockIdx.x * 256 + threadIdx.x;
  if (idx < 65536) {
    Wqk[idx] = (bh16)(idx < 32768 ? wq[idx] : wk[idx - 32768]);
  } else {
    const int j = idx - 65536;
    wvb[j] = (bh16)wv[j];
  }
  if (idx < 128) bias128[idx] = idx < 64 ? bq[idx] : bk[idx - 64];
}

// ---------- Q|K projection via MFMA ----------
// Q half -> Qb [B*N][64] row-major; K half -> Kf fragment-swizzled:
// Kf[b][jtile64][kgrp8][j64][8]  (kgrp = k>>3, elem = k&7)
__global__ __launch_bounds__(256) void qk_proj_k(const bh16* __restrict__ xTb,
                                                 const bh16* __restrict__ Wqk,
                                                 const float* __restrict__ bias128,
                                                 bh16* __restrict__ Qb,
                                                 bh16* __restrict__ Kf) {
  const int blk = blockIdx.x;  // 256 blocks of 64 rows
  const int t = threadIdx.x;
  const int w = t >> 6, l31 = t & 31, hi = (t & 63) >> 5;
  __shared__ __align__(16) bh16 As[2][64 * 64];  // [row][slot*8] rotated
  f32x16 acc[2];
#pragma unroll
  for (int nt = 0; nt < 2; nt++)
#pragma unroll
    for (int r = 0; r < 16; r++) acc[nt][r] = 0.0f;

#define QK_STAGE(kc, buf)                                                           \
  {                                                                                 \
    _Pragma("unroll") for (int i = 0; i < 2; i++) {                                 \
      const int s = i * 256 + t;                                                    \
      const int n = s >> 3, slot = s & 7;                                           \
      glds16(xTb + (size_t)(blk * 64 + n) * CIN + (kc) * 64 + (((slot + n) & 7) * 8), \
             &As[buf][(size_t)(i * 256 + w * 64) * 8]);                             \
    }                                                                               \
  }

  QK_STAGE(0, 0);
  __syncthreads();
  for (int kc = 0; kc < 8; kc++) {
    if (kc < 7) QK_STAGE(kc + 1, (kc + 1) & 1);
    const bh16* as = As[kc & 1];
#pragma unroll
    for (int ks = 0; ks < 4; ks++) {
      const bf16x8 bfr = *(const bf16x8*)(Wqk + (size_t)(w * 32 + l31) * CIN + kc * 64 + ks * 16 + hi * 8);
      const int kk = ks * 2 + hi;
#pragma unroll
      for (int nt = 0; nt < 2; nt++) {
        const int n = nt * 32 + l31;
        const bf16x8 a = *(const bf16x8*)&as[(size_t)(n * 8 + ((kk - n) & 7)) * 8];
        acc[nt] = __builtin_amdgcn_mfma_f32_32x32x16_bf16(a, bfr, acc[nt], 0, 0, 0);
      }
    }
    __syncthreads();
  }
#undef QK_STAGE
  const int o = w * 32 + l31;
  const float bo = bias128[o];
  if (w < 2) {
    // Q half: Qb[row][o]
#pragma unroll
    for (int nt = 0; nt < 2; nt++)
#pragma unroll
      for (int r = 0; r < 16; r++) {
        const int nloc = nt * 32 + (r & 3) + 8 * (r >> 2) + 4 * hi;
        Qb[(size_t)(blk * 64 + nloc) * 64 + o] = (bh16)(acc[nt][r] + bo);
      }
  } else {
    // K half: Kf[b][jtile][kg][j][8]
    const int b = blk >> 6, jtile = blk & 63;
    const int k = o - 64, kg = k >> 3, k7 = k & 7;
    bh16* kdst = Kf + (((size_t)(b * 64 + jtile) * 8 + kg) * 64) * 8 + k7;
#pragma unroll
    for (int nt = 0; nt < 2; nt++)
#pragma unroll
      for (int r = 0; r < 16; r++) {
        const int j = nt * 32 + (r & 3) + 8 * (r >> 2) + 4 * hi;
        kdst[(size_t)j * 8] = (bh16)(acc[nt][r] + bo);
      }
  }
}

// ---------- V projection via MFMA, output fragment-swizzled ----------
// Vf[b][ntile64][kgrp8][c512][8]  (kgrp = (n&63)>>3, elem = n&7)
__global__ __launch_bounds__(256) void v_proj_k(const bh16* __restrict__ xTb,
                                                const bh16* __restrict__ wvb,
                                                const float* __restrict__ bv,
                                                bh16* __restrict__ Vf) {
  const int nblk = blockIdx.x;  // 16
  const int cblk = blockIdx.y;  // 8
  const int b = blockIdx.z;
  const int t = threadIdx.x;
  const int w = t >> 6, l31 = t & 31, hi = (t & 63) >> 5;
  __shared__ __align__(16) bh16 Bs[2][256 * 64];  // [row n][slot*8] rotated
  f32x16 acc[2][2];
#pragma unroll
  for (int mt = 0; mt < 2; mt++)
#pragma unroll
    for (int nt = 0; nt < 2; nt++)
#pragma unroll
      for (int r = 0; r < 16; r++) acc[mt][nt][r] = 0.0f;

#define V_STAGE(kc, buf)                                                              \
  {                                                                                   \
    _Pragma("unroll") for (int i = 0; i < 8; i++) {                                   \
      const int s = i * 256 + t;                                                      \
      const int n = s >> 3, slot = s & 7;                                             \
      glds16(xTb + (size_t)(b * NPIX + nblk * 256 + n) * CIN + (kc) * 64 + (((slot + n) & 7) * 8), \
             &Bs[buf][(size_t)(i * 256 + w * 64) * 8]);                               \
    }                                                                                 \
  }

  V_STAGE(0, 0);
  __syncthreads();
  for (int kc = 0; kc < 8; kc++) {
    if (kc < 7) V_STAGE(kc + 1, (kc + 1) & 1);
    const bh16* bs = Bs[kc & 1];
#pragma unroll
    for (int ks = 0; ks < 4; ks++) {
      const int kk = ks * 2 + hi;
      bf16x8 a[2], bfr[2];
#pragma unroll
      for (int mt = 0; mt < 2; mt++)
        a[mt] = *(const bf16x8*)(wvb + (size_t)(cblk * 64 + mt * 32 + l31) * CIN + kc * 64 + ks * 16 + hi * 8);
#pragma unroll
      for (int nt = 0; nt < 2; nt++) {
        const int n = w * 64 + nt * 32 + l31;
        bfr[nt] = *(const bf16x8*)&bs[(size_t)(n * 8 + ((kk - n) & 7)) * 8];
      }
#pragma unroll
      for (int mt = 0; mt < 2; mt++)
#pragma unroll
        for (int nt = 0; nt < 2; nt++)
          acc[mt][nt] = __builtin_amdgcn_mfma_f32_32x32x16_bf16(a[mt], bfr[nt], acc[mt][nt], 0, 0, 0);
    }
    __syncthreads();
  }
#undef V_STAGE
  const int ntile0 = nblk * 4 + w;
#pragma unroll
  for (int mt = 0; mt < 2; mt++)
#pragma unroll
    for (int r = 0; r < 16; r++) {
      const int c = cblk * 64 + mt * 32 + (r & 3) + 8 * (r >> 2) + 4 * hi;
      const float bvc = bv[c];
#pragma unroll
      for (int nt = 0; nt < 2; nt++) {
        const int nl = nt * 32 + l31;  // n within the 64-tile
        Vf[(((size_t)(b * 64 + ntile0) * 8 + (nl >> 3)) * 512 + c) * 8 + (nl & 7)] =
            (bh16)(acc[mt][nt][r] + bvc);
      }
    }
}

// ---------- single-pass attention (no-max softmax) + residual -> pa [B][C][N] ----------
// BM=64 queries, BN=256 channels, XCD-aware block remap: all 64 blocks sharing
// one (b,cblk) V-strip (4 MB, == per-XCD L2) land on one XCD via id%8.
// K,V from fragment-swizzled Kf/Vf (coalesced), prefetched 1 iter ahead.
// Ps double-buffered -> ONE barrier per iteration.
__global__ __launch_bounds__(256, 2) void attn1p_k(const bh16* __restrict__ Qb,
                                                   const bh16* __restrict__ Kf,
                                                   const bh16* __restrict__ Vf,
                                                   const float* __restrict__ x,
                                                   float* __restrict__ pa) {
  // XCD-aware remap: id%8 selects (b,cblk); id/8 selects mblk.
  const int id = blockIdx.x + 2 * (blockIdx.y + 64 * blockIdx.z);
  const int b = (id & 7) >> 1;
  const int cblk = id & 1;
  const int mblk = (id >> 3) * 64;
  const int t = threadIdx.x;
  const int w = t >> 6, l31 = t & 31, hi = (t >> 5) & 1;
  const int jhalf = w & 1, mhalf = w >> 1;
  __shared__ __align__(16) bh16 Ps[2][8 * 64 * 8];  // [buf][slot][m][8]  8KB each
  __shared__ float lred[4][32];
  __shared__ float linvL[64];

  // Q fragments (B-operand, col m = mhalf*32+l31), fixed for whole block
  bf16x8 qf[4];
  {
    const bh16* qrow = Qb + (size_t)(b * NPIX + mblk + mhalf * 32 + l31) * 64;
#pragma unroll
    for (int ks = 0; ks < 4; ks++) qf[ks] = *(const bf16x8*)(qrow + ks * 16 + hi * 8);
  }
  const bh16* kfb = Kf + (size_t)b * (64 * 8 * 64 * 8);
  const bh16* vfb = Vf + (size_t)b * (64 * 8 * 512 * 8);
  const int cbase = cblk * 256 + w * 64;

  f32x16 acc[2][2];
#pragma unroll
  for (int mt = 0; mt < 2; mt++)
#pragma unroll
    for (int ct = 0; ct < 2; ct++)
#pragma unroll
      for (int r = 0; r < 16; r++) acc[mt][ct][r] = 0.0f;
  float lsum = 0.0f;

  // preload iter-0 K and V fragments (all coalesced: lanes contiguous)
  bf16x8 kf[4], vf[4][2];
#pragma unroll
  for (int ks = 0; ks < 4; ks++) {
    kf[ks] = *(const bf16x8*)(kfb + (((size_t)0 * 8 + ks * 2 + hi) * 64 + jhalf * 32 + l31) * 8);
#pragma unroll
    for (int ct = 0; ct < 2; ct++)
      vf[ks][ct] = *(const bf16x8*)(vfb + (((size_t)0 * 8 + ks * 2 + hi) * 512 + cbase + ct * 32 + l31) * 8);
  }

  for (int it = 0; it < 64; it++) {
    // GEMM1: S^T subtile (rows j = jhalf*32+.., cols m = mhalf*32+..)
    f32x16 s1;
#pragma unroll
    for (int r = 0; r < 16; r++) s1[r] = 0.0f;
#pragma unroll
    for (int ks = 0; ks < 4; ks++)
      s1 = __builtin_amdgcn_mfma_f32_32x32x16_bf16(kf[ks], qf[ks], s1, 0, 0, 0);
    // prefetch next iteration's K and V fragments
    bf16x8 kfn[4], vfn[4][2];
    if (it < 63) {
      const size_t nt1 = (size_t)(it + 1) * 8;
#pragma unroll
      for (int ks = 0; ks < 4; ks++) {
        kfn[ks] = *(const bf16x8*)(kfb + ((nt1 + ks * 2 + hi) * 64 + jhalf * 32 + l31) * 8);
#pragma unroll
        for (int ct = 0; ct < 2; ct++)
          vfn[ks][ct] = *(const bf16x8*)(vfb + ((nt1 + ks * 2 + hi) * 512 + cbase + ct * 32 + l31) * 8);
      }
    }
    // p = exp(s), accumulate row-sum, pack to Ps[buf]
    bh16* psw = Ps[it & 1];
#pragma unroll
    for (int g = 0; g < 4; g++) {
      union { bh16 h[4]; uint2 u2; } pk;
#pragma unroll
      for (int q = 0; q < 4; q++) {
        const float p = __expf(s1[g * 4 + q]);
        lsum += p;
        pk.h[q] = (bh16)p;
      }
      *(uint2*)(void*)&psw[(size_t)((jhalf * 4 + g) * 64 + mhalf * 32 + l31) * 8 + hi * 4] = pk.u2;
    }
    __syncthreads();  // Ps[buf] visible; dbuf makes the end-of-loop barrier unnecessary
    // GEMM2: O[m][c] += P[m][j] * V[j][c]
    const bh16* ps = Ps[it & 1];
#pragma unroll
    for (int ks = 0; ks < 4; ks++) {
      bf16x8 pf[2];
#pragma unroll
      for (int mt = 0; mt < 2; mt++)
        pf[mt] = *(const bf16x8*)&ps[(size_t)((ks * 2 + hi) * 64 + mt * 32 + l31) * 8];
#pragma unroll
      for (int mt = 0; mt < 2; mt++)
#pragma unroll
        for (int ct = 0; ct < 2; ct++)
          acc[mt][ct] = __builtin_amdgcn_mfma_f32_32x32x16_bf16(pf[mt], vf[ks][ct], acc[mt][ct], 0, 0, 0);
    }
    // rotate prefetched fragments
#pragma unroll
    for (int ks = 0; ks < 4; ks++) {
      kf[ks] = kfn[ks];
      vf[ks][0] = vfn[ks][0];
      vf[ks][1] = vfn[ks][1];
    }
  }

  // reduce row-sums: lanes (hi) within wave, then across jhalf wave pairs
  lsum += __shfl_xor(lsum, 32);
  if (hi == 0) lred[w][l31] = lsum;
  __syncthreads();
  if (t < 64) linvL[t] = 1.0f / (lred[(t >> 5) * 2][t & 31] + lred[(t >> 5) * 2 + 1][t & 31]);
  __syncthreads();

  // epilogue: normalize + residual, write pa[B][C][N]
#pragma unroll
  for (int mt = 0; mt < 2; mt++) {
#pragma unroll
    for (int g = 0; g < 4; g++) {
      const int mloc = mt * 32 + g * 8 + hi * 4;
      const float4 lv = *(const float4*)&linvL[mloc];
#pragma unroll
      for (int ct = 0; ct < 2; ct++) {
        const size_t base = (size_t)(b * CIN + cblk * 256 + w * 64 + ct * 32 + l31) * NPIX + mblk + mloc;
        const float4 xv = *(const float4*)&x[base];
        float4 r;
        r.x = acc[mt][ct][g * 4 + 0] * lv.x + xv.x;
        r.y = acc[mt][ct][g * 4 + 1] * lv.y + xv.y;
        r.z = acc[mt][ct][g * 4 + 2] * lv.z + xv.z;
        r.w = acc[mt][ct][g * 4 + 3] * lv.w + xv.w;
        *(float4*)&pa[base] = r;
      }
    }
  }
}

// ---------- pooling: avg+max per (b,c) row of pa [B][C][N] ----------
__global__ __launch_bounds__(256) void pool2_k(const float* __restrict__ pa,
                                               float* __restrict__ avgv,
                                               float* __restrict__ maxv) {
  const int t = threadIdx.x;
  const int row = blockIdx.x * 4 + (t >> 6);
  const int lane = t & 63;
  const float* base = pa + (size_t)row * NPIX;
  float s = 0.0f, mx = -1e30f;
#pragma unroll
  for (int i = 0; i < 16; i++) {
    const float4 v = *(const float4*)(base + i * 256 + lane * 4);
    s += v.x + v.y + v.z + v.w;
    mx = fmaxf(mx, fmaxf(fmaxf(v.x, v.y), fmaxf(v.z, v.w)));
  }
#pragma unroll
  for (int d = 1; d < 64; d <<= 1) {
    s += __shfl_xor(s, d);
    mx = fmaxf(mx, __shfl_xor(mx, d));
  }
  if (lane == 0) {
    avgv[row] = s * (1.0f / 4096.0f);
    maxv[row] = mx;
  }
}

// ---------- channel-attention MLP -> sigmoid scale ----------
__global__ __launch_bounds__(256) void mlp2_k(const float* __restrict__ avgv,
                                              const float* __restrict__ maxv,
                                              const float* __restrict__ w1,
                                              const float* __restrict__ w2,
                                              float* __restrict__ scale) {
  const int b = blockIdx.x;
  const int t = threadIdx.x;
  __shared__ float avg_l[CIN], max_l[CIN], hbuf[128];
#pragma unroll
  for (int h = 0; h < 2; h++) {
    const int c = t + h * 256;
    avg_l[c] = avgv[b * CIN + c];
    max_l[c] = maxv[b * CIN + c];
  }
  __syncthreads();
  if (t < 128) {
    const float* src = (t < 64) ? avg_l : max_l;
    const int o = t & 63;
    float sacc = 0.0f;
    for (int c = 0; c < CIN; c++) sacc += w1[o * CIN + c] * src[c];
    hbuf[t] = fmaxf(sacc, 0.0f);
  }
  __syncthreads();
#pragma unroll
  for (int h = 0; h < 2; h++) {
    const int c = t + h * 256;
    float sacc = 0.0f;
#pragma unroll
    for (int k = 0; k < 64; k++) sacc += w2[c * 64 + k] * (hbuf[k] + hbuf[64 + k]);
    scale[b * CIN + c] = 1.0f / (1.0f + __expf(-sacc));
  }
}

// ---------- pack pa*scale -> f16 padded pixel-major [B][66*66][512] ----------
__global__ __launch_bounds__(256) void pack_k(const float* __restrict__ pa,
                                              const float* __restrict__ scl,
                                              fh16* __restrict__ pab) {
  __shared__ float tile[32][65];
  const int n0 = blockIdx.x * 32;
  const int c0 = blockIdx.y * 64;
  const int b = blockIdx.z;
  const int t = threadIdx.x;
  {
    const int px = t & 31, cc = t >> 5;
#pragma unroll
    for (int i = 0; i < 8; i++) {
      const int c = cc * 8 + i;
      tile[px][c] = pa[((size_t)(b * CIN + c0 + c)) * NPIX + n0 + px] * scl[b * CIN + c0 + c];
    }
  }
  __syncthreads();
  {
    const int pixr = t >> 5, c2 = (t & 31) * 2;
#pragma unroll
    for (int j = 0; j < 4; j++) {
      const int pix = pixr + j * 8;
      const int n = n0 + pix;
      const int pp = ((n >> 6) + 1) * 66 + (n & 63) + 1;
      union { fh16 h[2]; unsigned int u; } pk;
      pk.h[0] = (fh16)tile[pix][c2];
      pk.h[1] = (fh16)tile[pix][c2 + 1];
      *(unsigned int*)(void*)(pab + ((size_t)b * PPIX + pp) * CIN + c0 + c2) = pk.u;
    }
  }
}

// ---------- repack conv weights -> f16 [oblk4][chunk32][tap9][o64][c16] ----------
__global__ __launch_bounds__(256) void wpack_k(const float* __restrict__ cw,
                                               fh16* __restrict__ wp) {
  const int d0 = (blockIdx.x * 256 + threadIdx.x) * 8;
  const int cc = d0 & 15;
  const int q = d0 >> 4;
  const int o = q & 63;
  const int q2 = q >> 6;
  const int tap = q2 % 9;
  const int q3 = q2 / 9;
  const int chunk = q3 & 31;
  const int oblk = q3 >> 5;
  const size_t sbase = (size_t)(oblk * 64 + o) * 4608 + (size_t)(chunk * 16 + cc) * 9 + tap;
  union { fh16 h[8]; uint4 u4; } pk;
#pragma unroll
  for (int i = 0; i < 8; i++) pk.h[i] = (fh16)cw[sbase + (size_t)i * 9];
  *(uint4*)(void*)(wp + d0) = pk.u4;
}

// ---------- implicit-GEMM 3x3 conv via f16 MFMA + BN + ReLU ----------
__global__ __launch_bounds__(256) void conv_mfma_k(const fh16* __restrict__ pab,
                                                   const fh16* __restrict__ wp,
                                                   const float* __restrict__ gamma,
                                                   const float* __restrict__ beta,
                                                   const float* __restrict__ mean,
                                                   const float* __restrict__ var,
                                                   float* __restrict__ out) {
  const int y0 = blockIdx.x * 4;
  const int oblk = blockIdx.y;
  const int b = blockIdx.z;
  const int t = threadIdx.x;
  const int w = t >> 6, lane = t & 63, l31 = lane & 31, hi = lane >> 5;
  __shared__ __align__(16) fh16 Xs[2][416 * 16];
  __shared__ __align__(16) fh16 Ws[2][9 * 64 * 16];
  __shared__ float sb[64], bb[64];
  if (t < 64) {
    const int o = oblk * 64 + t;
    const float inv = rsqrtf(var[o] + 1e-5f);
    const float sc = inv * gamma[o];
    sb[t] = sc;
    bb[t] = beta[o] - mean[o] * sc;
  }
  f32x16 o00, o01, o10, o11;
#pragma unroll
  for (int r = 0; r < 16; r++) { o00[r] = 0.0f; o01[r] = 0.0f; o10[r] = 0.0f; o11[r] = 0.0f; }

  const fh16* xbase = pab + ((size_t)b * PPIX + y0 * 66) * CIN + (lane >> 1) * CIN + (lane & 1) * 8;
  const fh16* wbase = wp + (size_t)oblk * 32 * 9216 + lane * 8;

#define STAGE(chunk, buf)                                                        \
  {                                                                              \
    const fh16* xs = xbase + (chunk) * 16;                                       \
    for (int i = w; i < 13; i += 4)                                              \
      glds16(xs + (size_t)i * 32 * CIN, &Xs[buf][i * 512]);                      \
    const fh16* wsrc = wbase + (size_t)(chunk) * 9216;                           \
    for (int i = w; i < 18; i += 4)                                              \
      glds16(wsrc + (size_t)i * 512, &Ws[buf][i * 512]);                         \
  }

  STAGE(0, 0);
  __syncthreads();
  for (int chunk = 0; chunk < 32; chunk++) {
    if (chunk < 31) STAGE(chunk + 1, (chunk + 1) & 1);
    const fh16* xs = Xs[chunk & 1];
    const fh16* ws = Ws[chunk & 1];
#pragma unroll
    for (int tap = 0; tap < 9; tap++) {
      const int ky = tap / 3, kx = tap - ky * 3;
      const f16x8 a0 = *(const f16x8*)&ws[tap * 1024 + l31 * 16 + hi * 8];
      const f16x8 a1 = *(const f16x8*)&ws[tap * 1024 + (32 + l31) * 16 + hi * 8];
      const int px = ((w + ky) * 66 + l31 + kx) * 16 + hi * 8;
      const f16x8 b0 = *(const f16x8*)&xs[px];
      const f16x8 b1 = *(const f16x8*)&xs[px + 32 * 16];
      o00 = __builtin_amdgcn_mfma_f32_32x32x16_f16(a0, b0, o00, 0, 0, 0);
      o01 = __builtin_amdgcn_mfma_f32_32x32x16_f16(a0, b1, o01, 0, 0, 0);
      o10 = __builtin_amdgcn_mfma_f32_32x32x16_f16(a1, b0, o10, 0, 0, 0);
      o11 = __builtin_amdgcn_mfma_f32_32x32x16_f16(a1, b1, o11, 0, 0, 0);
    }
    __syncthreads();
  }
#undef STAGE

  const f32x16* accs[2][2] = {{&o00, &o01}, {&o10, &o11}};
#pragma unroll
  for (int mt = 0; mt < 2; mt++) {
#pragma unroll
    for (int nt = 0; nt < 2; nt++) {
      const f32x16& A = *accs[mt][nt];
#pragma unroll
      for (int r = 0; r < 16; r++) {
        const int cl = mt * 32 + (r & 3) + 8 * (r >> 2) + 4 * hi;
        const int pix = nt * 32 + l31;
        const float y = A[r] * sb[cl] + bb[cl];
        out[((size_t)(b * COUT + oblk * 64 + cl)) * NPIX + (y0 + w) * 64 + pix] = fmaxf(y, 0.0f);
      }
    }
  }
}

extern "C" void kernel_launch(void* const* d_in, const int* in_sizes, int n_in,
                              void* d_out, int out_size, void* d_ws, size_t ws_size,
                              hipStream_t stream) {
  (void)in_sizes; (void)n_in; (void)out_size; (void)ws_size;
  const float* x        = (const float*)d_in[0];
  const float* wq       = (const float*)d_in[1];
  const float* bq       = (const float*)d_in[2];
  const float* wk       = (const float*)d_in[3];
  const float* bk       = (const float*)d_in[4];
  const float* wv       = (const float*)d_in[5];
  const float* bv       = (const float*)d_in[6];
  const float* ca_w1    = (const float*)d_in[7];
  const float* ca_w2    = (const float*)d_in[8];
  const float* conv_w   = (const float*)d_in[9];
  const float* bn_gamma = (const float*)d_in[10];
  const float* bn_beta  = (const float*)d_in[11];
  const float* bn_mean  = (const float*)d_in[12];
  const float* bn_var   = (const float*)d_in[13];
  float* out = (float*)d_out;

  float* ws = (float*)d_ws;
  float* pa      = ws;                          // [B][C][N] fp32
  bh16*  Vf      = (bh16*)(ws + 8388608);       // [B][64][8][512][8] bf16 (aliased by wpck later)
  fh16*  wpck    = (fh16*)(ws + 8388608);       // conv weights f16 (after attn)
  bh16*  Qb      = (bh16*)(ws + 12582912);      // [B*N][64] bf16
  bh16*  Kf      = (bh16*)(ws + 13107200);      // [B][64][8][64][8] bf16
  bh16*  xTb     = (bh16*)(ws + 13631488);      // [B][N][C] bf16 (aliased by pab later)
  fh16*  pab     = (fh16*)(ws + 13631488);      // [B][4356][512] f16 + pad
  bh16*  Wqk     = (bh16*)(ws + 17825792);      // [128][512] bf16
  bh16*  wvb     = (bh16*)(ws + 17858560);      // [512][512] bf16
  float* bias128 = ws + 17989632;
  float* avgv    = ws + 18100224;
  float* maxv    = ws + 18102272;
  float* scl     = ws + 18104320;

  wcast_k<<<dim3(1280, 1, 1), 256, 0, stream>>>(wq, wk, wv, bq, bk, Wqk, wvb, bias128);
  transpose_bf_k<<<dim3(NPIX / 32, CIN / 32, NB), dim3(32, 8, 1), 0, stream>>>(x, xTb, CIN, NPIX);
  qk_proj_k<<<dim3(256, 1, 1), 256, 0, stream>>>(xTb, Wqk, bias128, Qb, Kf);
  v_proj_k<<<dim3(16, 8, NB), 256, 0, stream>>>(xTb, wvb, bv, Vf);
  attn1p_k<<<dim3(2, 64, NB), 256, 0, stream>>>(Qb, Kf, Vf, x, pa);
  // xTb dead now: zero pab (incl. borders + tail pad)
  hipMemsetAsync(pab, 0, (size_t)(NB * PPIX * CIN + 16384) * sizeof(fh16), stream);
  pool2_k<<<dim3(512, 1, 1), 256, 0, stream>>>(pa, avgv, maxv);
  mlp2_k<<<dim3(NB, 1, 1), 256, 0, stream>>>(avgv, maxv, ca_w1, ca_w2, scl);
  pack_k<<<dim3(NPIX / 32, CIN / 64, NB), 256, 0, stream>>>(pa, scl, pab);
  wpack_k<<<dim3(576, 1, 1), 256, 0, stream>>>(conv_w, wpck);  // Vf dead now
  conv_mfma_k<<<dim3(16, 4, NB), 256, 0, stream>>>(pab, wpck, bn_gamma, bn_beta,
                                                   bn_mean, bn_var, out);
}

// Round 8
// 339.715 us; speedup vs baseline: 1.0061x; 1.0061x over previous
//
#include <hip/hip_runtime.h>

#define NB 4
#define CIN 512
#define NPIX 4096
#define CQK 64
#define COUT 256
#define PPIX 4356   // 66*66 padded pixels

typedef __bf16 bh16;
typedef _Float16 fh16;
typedef __attribute__((ext_vector_type(8))) __bf16 bf16x8;
typedef __attribute__((ext_vector_type(8))) _Float16 f16x8;
typedef __attribute__((ext_vector_type(16))) float f32x16;

#define AS1 __attribute__((address_space(1)))
#define AS3 __attribute__((address_space(3)))

__device__ __forceinline__ void glds16(const void* g, void* l) {
  __builtin_amdgcn_global_load_lds((const AS1 unsigned int*)g, (AS3 unsigned int*)l, 16, 0, 0);
}

// ---------- transpose x [B][C][N] -> xTb [B][N][C] bf16 ----------
__global__ __launch_bounds__(256) void transpose_bf_k(const float* __restrict__ src,
                                                      bh16* __restrict__ dst,
                                                      int rows, int cols) {
  __shared__ float tile[32][33];
  const int b = blockIdx.z;
  const int c0 = blockIdx.x * 32;   // over cols (N)
  const int r0 = blockIdx.y * 32;   // over rows (C)
  const float* s = src + (size_t)b * rows * cols;
  bh16* d = dst + (size_t)b * rows * cols;
  const int tx = threadIdx.x, ty = threadIdx.y;  // 32 x 8
#pragma unroll
  for (int i = 0; i < 32; i += 8)
    tile[ty + i][tx] = s[(size_t)(r0 + ty + i) * cols + (c0 + tx)];
  __syncthreads();
#pragma unroll
  for (int i = 0; i < 32; i += 8)
    d[(size_t)(c0 + ty + i) * rows + (r0 + tx)] = (bh16)tile[tx][ty + i];
}

// ---------- cast weights to bf16: Wqk[128][512] = [wq;wk], wvb[512][512], bias128 ----------
__global__ __launch_bounds__(256) void wcast_k(const float* __restrict__ wq,
                                               const float* __restrict__ wk,
                                               const float* __restrict__ wv,
                                               const float* __restrict__ bq,
                                               const float* __restrict__ bk,
                                               bh16* __restrict__ Wqk,
                                               bh16* __restrict__ wvb,
                                               float* __restrict__ bias128) {
  const int idx = blockIdx.x * 256 + threadIdx.x;
  if (idx < 65536) {
    Wqk[idx] = (bh16)(idx < 32768 ? wq[idx] : wk[idx - 32768]);
  } else {
    const int j = idx - 65536;
    wvb[j] = (bh16)wv[j];
  }
  if (idx < 128) bias128[idx] = idx < 64 ? bq[idx] : bk[idx - 64];
}

// ---------- Q|K projection via MFMA ----------
// Q half -> Qb [B*N][64] row-major; K half -> Kf fragment-swizzled:
// Kf[b][jtile64][kgrp8][j64][8]  (kgrp = k>>3, elem = k&7)
__global__ __launch_bounds__(256) void qk_proj_k(const bh16* __restrict__ xTb,
                                                 const bh16* __restrict__ Wqk,
                                                 const float* __restrict__ bias128,
                                                 bh16* __restrict__ Qb,
                                                 bh16* __restrict__ Kf) {
  const int blk = blockIdx.x;  // 256 blocks of 64 rows
  const int t = threadIdx.x;
  const int w = t >> 6, l31 = t & 31, hi = (t & 63) >> 5;
  __shared__ __align__(16) bh16 As[2][64 * 64];  // [row][slot*8] rotated
  f32x16 acc[2];
#pragma unroll
  for (int nt = 0; nt < 2; nt++)
#pragma unroll
    for (int r = 0; r < 16; r++) acc[nt][r] = 0.0f;

#define QK_STAGE(kc, buf)                                                           \
  {                                                                                 \
    _Pragma("unroll") for (int i = 0; i < 2; i++) {                                 \
      const int s = i * 256 + t;                                                    \
      const int n = s >> 3, slot = s & 7;                                           \
      glds16(xTb + (size_t)(blk * 64 + n) * CIN + (kc) * 64 + (((slot + n) & 7) * 8), \
             &As[buf][(size_t)(i * 256 + w * 64) * 8]);                             \
    }                                                                               \
  }

  QK_STAGE(0, 0);
  __syncthreads();
  for (int kc = 0; kc < 8; kc++) {
    if (kc < 7) QK_STAGE(kc + 1, (kc + 1) & 1);
    const bh16* as = As[kc & 1];
#pragma unroll
    for (int ks = 0; ks < 4; ks++) {
      const bf16x8 bfr = *(const bf16x8*)(Wqk + (size_t)(w * 32 + l31) * CIN + kc * 64 + ks * 16 + hi * 8);
      const int kk = ks * 2 + hi;
#pragma unroll
      for (int nt = 0; nt < 2; nt++) {
        const int n = nt * 32 + l31;
        const bf16x8 a = *(const bf16x8*)&as[(size_t)(n * 8 + ((kk - n) & 7)) * 8];
        acc[nt] = __builtin_amdgcn_mfma_f32_32x32x16_bf16(a, bfr, acc[nt], 0, 0, 0);
      }
    }
    __syncthreads();
  }
#undef QK_STAGE
  const int o = w * 32 + l31;
  const float bo = bias128[o];
  if (w < 2) {
    // Q half: Qb[row][o]
#pragma unroll
    for (int nt = 0; nt < 2; nt++)
#pragma unroll
      for (int r = 0; r < 16; r++) {
        const int nloc = nt * 32 + (r & 3) + 8 * (r >> 2) + 4 * hi;
        Qb[(size_t)(blk * 64 + nloc) * 64 + o] = (bh16)(acc[nt][r] + bo);
      }
  } else {
    // K half: Kf[b][jtile][kg][j][8]
    const int b = blk >> 6, jtile = blk & 63;
    const int k = o - 64, kg = k >> 3, k7 = k & 7;
    bh16* kdst = Kf + (((size_t)(b * 64 + jtile) * 8 + kg) * 64) * 8 + k7;
#pragma unroll
    for (int nt = 0; nt < 2; nt++)
#pragma unroll
      for (int r = 0; r < 16; r++) {
        const int j = nt * 32 + (r & 3) + 8 * (r >> 2) + 4 * hi;
        kdst[(size_t)j * 8] = (bh16)(acc[nt][r] + bo);
      }
  }
}

// ---------- V projection via MFMA, output fragment-swizzled ----------
// Vf[b][ntile64][kgrp8][c512][8]  (kgrp = (n&63)>>3, elem = n&7)
__global__ __launch_bounds__(256) void v_proj_k(const bh16* __restrict__ xTb,
                                                const bh16* __restrict__ wvb,
                                                const float* __restrict__ bv,
                                                bh16* __restrict__ Vf) {
  const int nblk = blockIdx.x;  // 16
  const int cblk = blockIdx.y;  // 8
  const int b = blockIdx.z;
  const int t = threadIdx.x;
  const int w = t >> 6, l31 = t & 31, hi = (t & 63) >> 5;
  __shared__ __align__(16) bh16 Bs[2][256 * 64];  // [row n][slot*8] rotated
  f32x16 acc[2][2];
#pragma unroll
  for (int mt = 0; mt < 2; mt++)
#pragma unroll
    for (int nt = 0; nt < 2; nt++)
#pragma unroll
      for (int r = 0; r < 16; r++) acc[mt][nt][r] = 0.0f;

#define V_STAGE(kc, buf)                                                              \
  {                                                                                   \
    _Pragma("unroll") for (int i = 0; i < 8; i++) {                                   \
      const int s = i * 256 + t;                                                      \
      const int n = s >> 3, slot = s & 7;                                             \
      glds16(xTb + (size_t)(b * NPIX + nblk * 256 + n) * CIN + (kc) * 64 + (((slot + n) & 7) * 8), \
             &Bs[buf][(size_t)(i * 256 + w * 64) * 8]);                               \
    }                                                                                 \
  }

  V_STAGE(0, 0);
  __syncthreads();
  for (int kc = 0; kc < 8; kc++) {
    if (kc < 7) V_STAGE(kc + 1, (kc + 1) & 1);
    const bh16* bs = Bs[kc & 1];
#pragma unroll
    for (int ks = 0; ks < 4; ks++) {
      const int kk = ks * 2 + hi;
      bf16x8 a[2], bfr[2];
#pragma unroll
      for (int mt = 0; mt < 2; mt++)
        a[mt] = *(const bf16x8*)(wvb + (size_t)(cblk * 64 + mt * 32 + l31) * CIN + kc * 64 + ks * 16 + hi * 8);
#pragma unroll
      for (int nt = 0; nt < 2; nt++) {
        const int n = w * 64 + nt * 32 + l31;
        bfr[nt] = *(const bf16x8*)&bs[(size_t)(n * 8 + ((kk - n) & 7)) * 8];
      }
#pragma unroll
      for (int mt = 0; mt < 2; mt++)
#pragma unroll
        for (int nt = 0; nt < 2; nt++)
          acc[mt][nt] = __builtin_amdgcn_mfma_f32_32x32x16_bf16(a[mt], bfr[nt], acc[mt][nt], 0, 0, 0);
    }
    __syncthreads();
  }
#undef V_STAGE
  const int ntile0 = nblk * 4 + w;
#pragma unroll
  for (int mt = 0; mt < 2; mt++)
#pragma unroll
    for (int r = 0; r < 16; r++) {
      const int c = cblk * 64 + mt * 32 + (r & 3) + 8 * (r >> 2) + 4 * hi;
      const float bvc = bv[c];
#pragma unroll
      for (int nt = 0; nt < 2; nt++) {
        const int nl = nt * 32 + l31;  // n within the 64-tile
        Vf[(((size_t)(b * 64 + ntile0) * 8 + (nl >> 3)) * 512 + c) * 8 + (nl & 7)] =
            (bh16)(acc[mt][nt][r] + bvc);
      }
    }
}

// ---------- single-pass attention (no-max softmax) + residual -> pa [B][C][N] ----------
// BM=64, BN=256, XCD-aware remap. Software-pipelined: GEMM2 delayed one j-tile so
// each iteration issues G1(it+1)+G2(it-1) [MFMA] concurrently with exp/pack(it)
// [VALU] -- all independent, dual-pipe issue within each wave. 1 barrier/iter.
__global__ __launch_bounds__(256, 2) void attn1p_k(const bh16* __restrict__ Qb,
                                                   const bh16* __restrict__ Kf,
                                                   const bh16* __restrict__ Vf,
                                                   const float* __restrict__ x,
                                                   float* __restrict__ pa) {
  // XCD-aware remap: id%8 selects (b,cblk); id/8 selects mblk.
  const int id = blockIdx.x + 2 * (blockIdx.y + 64 * blockIdx.z);
  const int b = (id & 7) >> 1;
  const int cblk = id & 1;
  const int mblk = (id >> 3) * 64;
  const int t = threadIdx.x;
  const int w = t >> 6, l31 = t & 31, hi = (t >> 5) & 1;
  const int jhalf = w & 1, mhalf = w >> 1;
  __shared__ __align__(16) bh16 Ps[2][8 * 64 * 8];  // [buf][slot][m][8]  8KB each
  __shared__ float lred[4][32];
  __shared__ float linvL[64];

  // Q fragments (B-operand, col m = mhalf*32+l31), fixed for whole block
  bf16x8 qf[4];
  {
    const bh16* qrow = Qb + (size_t)(b * NPIX + mblk + mhalf * 32 + l31) * 64;
#pragma unroll
    for (int ks = 0; ks < 4; ks++) qf[ks] = *(const bf16x8*)(qrow + ks * 16 + hi * 8);
  }
  const bh16* kfb = Kf + (size_t)b * (64 * 8 * 64 * 8);
  const bh16* vfb = Vf + (size_t)b * (64 * 8 * 512 * 8);
  const int cbase = cblk * 256 + w * 64;

#define KADDR(tile, ks) (kfb + (((size_t)(tile) * 8 + (ks) * 2 + hi) * 64 + jhalf * 32 + l31) * 8)
#define VADDR(tile, ks, ct) (vfb + (((size_t)(tile) * 8 + (ks) * 2 + hi) * 512 + cbase + (ct) * 32 + l31) * 8)

  f32x16 acc[2][2];
#pragma unroll
  for (int mt = 0; mt < 2; mt++)
#pragma unroll
    for (int ct = 0; ct < 2; ct++)
#pragma unroll
      for (int r = 0; r < 16; r++) acc[mt][ct][r] = 0.0f;
  float lsum = 0.0f;

  // pipeline registers
  bf16x8 kf_nxt[4], kf_fly[4];      // K(it+1), K(it+2)
  bf16x8 vf_use[4][2], vf_rdy[4][2];  // V(it-1) [G2 this iter], V(it)
  f32x16 s1;                         // raw S(it)
  {
    bf16x8 k0[4];
#pragma unroll
    for (int ks = 0; ks < 4; ks++) {
      k0[ks] = *(const bf16x8*)KADDR(0, ks);
#pragma unroll
      for (int ct = 0; ct < 2; ct++) vf_rdy[ks][ct] = *(const bf16x8*)VADDR(0, ks, ct);
    }
#pragma unroll
    for (int ks = 0; ks < 4; ks++) {
      kf_nxt[ks] = *(const bf16x8*)KADDR(1, ks);
      kf_fly[ks] = *(const bf16x8*)KADDR(2, ks);
    }
#pragma unroll
    for (int r = 0; r < 16; r++) s1[r] = 0.0f;
#pragma unroll
    for (int ks = 0; ks < 4; ks++)
      s1 = __builtin_amdgcn_mfma_f32_32x32x16_bf16(k0[ks], qf[ks], s1, 0, 0, 0);
  }

  for (int it = 0; it < 64; it++) {
    // G1 for it+1 (result for next iteration; garbage at it=63, unused)
    f32x16 s1n;
#pragma unroll
    for (int r = 0; r < 16; r++) s1n[r] = 0.0f;
#pragma unroll
    for (int ks = 0; ks < 4; ks++)
      s1n = __builtin_amdgcn_mfma_f32_32x32x16_bf16(kf_nxt[ks], qf[ks], s1n, 0, 0, 0);

    const bh16* ps = Ps[(it + 1) & 1];  // == (it-1)&1
    bh16* psw = Ps[it & 1];
    if (it) {
      // G2(it-1) [MFMA] interleaved with exp/pack(it) [VALU] -- independent
#pragma unroll
      for (int ks = 0; ks < 4; ks++) {
        bf16x8 pf0 = *(const bf16x8*)&ps[(size_t)((ks * 2 + hi) * 64 + l31) * 8];
        bf16x8 pf1 = *(const bf16x8*)&ps[(size_t)((ks * 2 + hi) * 64 + 32 + l31) * 8];
        acc[0][0] = __builtin_amdgcn_mfma_f32_32x32x16_bf16(pf0, vf_use[ks][0], acc[0][0], 0, 0, 0);
        acc[0][1] = __builtin_amdgcn_mfma_f32_32x32x16_bf16(pf0, vf_use[ks][1], acc[0][1], 0, 0, 0);
        // one exp/pack group between MFMA clusters
        {
          union { bh16 h[4]; uint2 u2; } pk;
#pragma unroll
          for (int q = 0; q < 4; q++) {
            const float p = __expf(s1[ks * 4 + q]);
            lsum += p;
            pk.h[q] = (bh16)p;
          }
          *(uint2*)(void*)&psw[(size_t)((jhalf * 4 + ks) * 64 + mhalf * 32 + l31) * 8 + hi * 4] = pk.u2;
        }
        acc[1][0] = __builtin_amdgcn_mfma_f32_32x32x16_bf16(pf1, vf_use[ks][0], acc[1][0], 0, 0, 0);
        acc[1][1] = __builtin_amdgcn_mfma_f32_32x32x16_bf16(pf1, vf_use[ks][1], acc[1][1], 0, 0, 0);
      }
    } else {
#pragma unroll
      for (int g = 0; g < 4; g++) {
        union { bh16 h[4]; uint2 u2; } pk;
#pragma unroll
        for (int q = 0; q < 4; q++) {
          const float p = __expf(s1[g * 4 + q]);
          lsum += p;
          pk.h[q] = (bh16)p;
        }
        *(uint2*)(void*)&psw[(size_t)((jhalf * 4 + g) * 64 + mhalf * 32 + l31) * 8 + hi * 4] = pk.u2;
      }
    }
    __syncthreads();  // P(it) visible; loads below get a full iteration of cover
    // rotate pipeline + issue prefetches
    s1 = s1n;
    const int kt = (it + 3 < 64) ? it + 3 : 63;
    const int vt = (it + 1 < 64) ? it + 1 : 63;
#pragma unroll
    for (int ks = 0; ks < 4; ks++) {
      kf_nxt[ks] = kf_fly[ks];
      kf_fly[ks] = *(const bf16x8*)KADDR(kt, ks);
      vf_use[ks][0] = vf_rdy[ks][0];
      vf_use[ks][1] = vf_rdy[ks][1];
      vf_rdy[ks][0] = *(const bf16x8*)VADDR(vt, ks, 0);
      vf_rdy[ks][1] = *(const bf16x8*)VADDR(vt, ks, 1);
    }
  }
  // final G2: P(63) x V(63)
  {
    const bh16* ps = Ps[1];
#pragma unroll
    for (int ks = 0; ks < 4; ks++) {
      bf16x8 pf0 = *(const bf16x8*)&ps[(size_t)((ks * 2 + hi) * 64 + l31) * 8];
      bf16x8 pf1 = *(const bf16x8*)&ps[(size_t)((ks * 2 + hi) * 64 + 32 + l31) * 8];
      acc[0][0] = __builtin_amdgcn_mfma_f32_32x32x16_bf16(pf0, vf_use[ks][0], acc[0][0], 0, 0, 0);
      acc[0][1] = __builtin_amdgcn_mfma_f32_32x32x16_bf16(pf0, vf_use[ks][1], acc[0][1], 0, 0, 0);
      acc[1][0] = __builtin_amdgcn_mfma_f32_32x32x16_bf16(pf1, vf_use[ks][0], acc[1][0], 0, 0, 0);
      acc[1][1] = __builtin_amdgcn_mfma_f32_32x32x16_bf16(pf1, vf_use[ks][1], acc[1][1], 0, 0, 0);
    }
  }
#undef KADDR
#undef VADDR

  // reduce row-sums: lanes (hi) within wave, then across jhalf wave pairs
  lsum += __shfl_xor(lsum, 32);
  if (hi == 0) lred[w][l31] = lsum;
  __syncthreads();
  if (t < 64) linvL[t] = 1.0f / (lred[(t >> 5) * 2][t & 31] + lred[(t >> 5) * 2 + 1][t & 31]);
  __syncthreads();

  // epilogue: normalize + residual, write pa[B][C][N]
#pragma unroll
  for (int mt = 0; mt < 2; mt++) {
#pragma unroll
    for (int g = 0; g < 4; g++) {
      const int mloc = mt * 32 + g * 8 + hi * 4;
      const float4 lv = *(const float4*)&linvL[mloc];
#pragma unroll
      for (int ct = 0; ct < 2; ct++) {
        const size_t base = (size_t)(b * CIN + cblk * 256 + w * 64 + ct * 32 + l31) * NPIX + mblk + mloc;
        const float4 xv = *(const float4*)&x[base];
        float4 r;
        r.x = acc[mt][ct][g * 4 + 0] * lv.x + xv.x;
        r.y = acc[mt][ct][g * 4 + 1] * lv.y + xv.y;
        r.z = acc[mt][ct][g * 4 + 2] * lv.z + xv.z;
        r.w = acc[mt][ct][g * 4 + 3] * lv.w + xv.w;
        *(float4*)&pa[base] = r;
      }
    }
  }
}

// ---------- pooling: avg+max per (b,c) row of pa [B][C][N] ----------
__global__ __launch_bounds__(256) void pool2_k(const float* __restrict__ pa,
                                               float* __restrict__ avgv,
                                               float* __restrict__ maxv) {
  const int t = threadIdx.x;
  const int row = blockIdx.x * 4 + (t >> 6);
  const int lane = t & 63;
  const float* base = pa + (size_t)row * NPIX;
  float s = 0.0f, mx = -1e30f;
#pragma unroll
  for (int i = 0; i < 16; i++) {
    const float4 v = *(const float4*)(base + i * 256 + lane * 4);
    s += v.x + v.y + v.z + v.w;
    mx = fmaxf(mx, fmaxf(fmaxf(v.x, v.y), fmaxf(v.z, v.w)));
  }
#pragma unroll
  for (int d = 1; d < 64; d <<= 1) {
    s += __shfl_xor(s, d);
    mx = fmaxf(mx, __shfl_xor(mx, d));
  }
  if (lane == 0) {
    avgv[row] = s * (1.0f / 4096.0f);
    maxv[row] = mx;
  }
}

// ---------- channel-attention MLP -> sigmoid scale ----------
__global__ __launch_bounds__(256) void mlp2_k(const float* __restrict__ avgv,
                                              const float* __restrict__ maxv,
                                              const float* __restrict__ w1,
                                              const float* __restrict__ w2,
                                              float* __restrict__ scale) {
  const int b = blockIdx.x;
  const int t = threadIdx.x;
  __shared__ float avg_l[CIN], max_l[CIN], hbuf[128];
#pragma unroll
  for (int h = 0; h < 2; h++) {
    const int c = t + h * 256;
    avg_l[c] = avgv[b * CIN + c];
    max_l[c] = maxv[b * CIN + c];
  }
  __syncthreads();
  if (t < 128) {
    const float* src = (t < 64) ? avg_l : max_l;
    const int o = t & 63;
    float sacc = 0.0f;
    for (int c = 0; c < CIN; c++) sacc += w1[o * CIN + c] * src[c];
    hbuf[t] = fmaxf(sacc, 0.0f);
  }
  __syncthreads();
#pragma unroll
  for (int h = 0; h < 2; h++) {
    const int c = t + h * 256;
    float sacc = 0.0f;
#pragma unroll
    for (int k = 0; k < 64; k++) sacc += w2[c * 64 + k] * (hbuf[k] + hbuf[64 + k]);
    scale[b * CIN + c] = 1.0f / (1.0f + __expf(-sacc));
  }
}

// ---------- pack pa*scale -> f16 padded pixel-major [B][66*66][512] ----------
__global__ __launch_bounds__(256) void pack_k(const float* __restrict__ pa,
                                              const float* __restrict__ scl,
                                              fh16* __restrict__ pab) {
  __shared__ float tile[32][65];
  const int n0 = blockIdx.x * 32;
  const int c0 = blockIdx.y * 64;
  const int b = blockIdx.z;
  const int t = threadIdx.x;
  {
    const int px = t & 31, cc = t >> 5;
#pragma unroll
    for (int i = 0; i < 8; i++) {
      const int c = cc * 8 + i;
      tile[px][c] = pa[((size_t)(b * CIN + c0 + c)) * NPIX + n0 + px] * scl[b * CIN + c0 + c];
    }
  }
  __syncthreads();
  {
    const int pixr = t >> 5, c2 = (t & 31) * 2;
#pragma unroll
    for (int j = 0; j < 4; j++) {
      const int pix = pixr + j * 8;
      const int n = n0 + pix;
      const int pp = ((n >> 6) + 1) * 66 + (n & 63) + 1;
      union { fh16 h[2]; unsigned int u; } pk;
      pk.h[0] = (fh16)tile[pix][c2];
      pk.h[1] = (fh16)tile[pix][c2 + 1];
      *(unsigned int*)(void*)(pab + ((size_t)b * PPIX + pp) * CIN + c0 + c2) = pk.u;
    }
  }
}

// ---------- repack conv weights -> f16 [oblk4][chunk32][tap9][o64][c16] ----------
__global__ __launch_bounds__(256) void wpack_k(const float* __restrict__ cw,
                                               fh16* __restrict__ wp) {
  const int d0 = (blockIdx.x * 256 + threadIdx.x) * 8;
  const int cc = d0 & 15;
  const int q = d0 >> 4;
  const int o = q & 63;
  const int q2 = q >> 6;
  const int tap = q2 % 9;
  const int q3 = q2 / 9;
  const int chunk = q3 & 31;
  const int oblk = q3 >> 5;
  const size_t sbase = (size_t)(oblk * 64 + o) * 4608 + (size_t)(chunk * 16 + cc) * 9 + tap;
  union { fh16 h[8]; uint4 u4; } pk;
#pragma unroll
  for (int i = 0; i < 8; i++) pk.h[i] = (fh16)cw[sbase + (size_t)i * 9];
  *(uint4*)(void*)(wp + d0) = pk.u4;
}

// ---------- implicit-GEMM 3x3 conv via f16 MFMA + BN + ReLU ----------
__global__ __launch_bounds__(256) void conv_mfma_k(const fh16* __restrict__ pab,
                                                   const fh16* __restrict__ wp,
                                                   const float* __restrict__ gamma,
                                                   const float* __restrict__ beta,
                                                   const float* __restrict__ mean,
                                                   const float* __restrict__ var,
                                                   float* __restrict__ out) {
  const int y0 = blockIdx.x * 4;
  const int oblk = blockIdx.y;
  const int b = blockIdx.z;
  const int t = threadIdx.x;
  const int w = t >> 6, lane = t & 63, l31 = lane & 31, hi = lane >> 5;
  __shared__ __align__(16) fh16 Xs[2][416 * 16];
  __shared__ __align__(16) fh16 Ws[2][9 * 64 * 16];
  __shared__ float sb[64], bb[64];
  if (t < 64) {
    const int o = oblk * 64 + t;
    const float inv = rsqrtf(var[o] + 1e-5f);
    const float sc = inv * gamma[o];
    sb[t] = sc;
    bb[t] = beta[o] - mean[o] * sc;
  }
  f32x16 o00, o01, o10, o11;
#pragma unroll
  for (int r = 0; r < 16; r++) { o00[r] = 0.0f; o01[r] = 0.0f; o10[r] = 0.0f; o11[r] = 0.0f; }

  const fh16* xbase = pab + ((size_t)b * PPIX + y0 * 66) * CIN + (lane >> 1) * CIN + (lane & 1) * 8;
  const fh16* wbase = wp + (size_t)oblk * 32 * 9216 + lane * 8;

#define STAGE(chunk, buf)                                                        \
  {                                                                              \
    const fh16* xs = xbase + (chunk) * 16;                                       \
    for (int i = w; i < 13; i += 4)                                              \
      glds16(xs + (size_t)i * 32 * CIN, &Xs[buf][i * 512]);                      \
    const fh16* wsrc = wbase + (size_t)(chunk) * 9216;                           \
    for (int i = w; i < 18; i += 4)                                              \
      glds16(wsrc + (size_t)i * 512, &Ws[buf][i * 512]);                         \
  }

  STAGE(0, 0);
  __syncthreads();
  for (int chunk = 0; chunk < 32; chunk++) {
    if (chunk < 31) STAGE(chunk + 1, (chunk + 1) & 1);
    const fh16* xs = Xs[chunk & 1];
    const fh16* ws = Ws[chunk & 1];
#pragma unroll
    for (int tap = 0; tap < 9; tap++) {
      const int ky = tap / 3, kx = tap - ky * 3;
      const f16x8 a0 = *(const f16x8*)&ws[tap * 1024 + l31 * 16 + hi * 8];
      const f16x8 a1 = *(const f16x8*)&ws[tap * 1024 + (32 + l31) * 16 + hi * 8];
      const int px = ((w + ky) * 66 + l31 + kx) * 16 + hi * 8;
      const f16x8 b0 = *(const f16x8*)&xs[px];
      const f16x8 b1 = *(const f16x8*)&xs[px + 32 * 16];
      o00 = __builtin_amdgcn_mfma_f32_32x32x16_f16(a0, b0, o00, 0, 0, 0);
      o01 = __builtin_amdgcn_mfma_f32_32x32x16_f16(a0, b1, o01, 0, 0, 0);
      o10 = __builtin_amdgcn_mfma_f32_32x32x16_f16(a1, b0, o10, 0, 0, 0);
      o11 = __builtin_amdgcn_mfma_f32_32x32x16_f16(a1, b1, o11, 0, 0, 0);
    }
    __syncthreads();
  }
#undef STAGE

  const f32x16* accs[2][2] = {{&o00, &o01}, {&o10, &o11}};
#pragma unroll
  for (int mt = 0; mt < 2; mt++) {
#pragma unroll
    for (int nt = 0; nt < 2; nt++) {
      const f32x16& A = *accs[mt][nt];
#pragma unroll
      for (int r = 0; r < 16; r++) {
        const int cl = mt * 32 + (r & 3) + 8 * (r >> 2) + 4 * hi;
        const int pix = nt * 32 + l31;
        const float y = A[r] * sb[cl] + bb[cl];
        out[((size_t)(b * COUT + oblk * 64 + cl)) * NPIX + (y0 + w) * 64 + pix] = fmaxf(y, 0.0f);
      }
    }
  }
}

extern "C" void kernel_launch(void* const* d_in, const int* in_sizes, int n_in,
                              void* d_out, int out_size, void* d_ws, size_t ws_size,
                              hipStream_t stream) {
  (void)in_sizes; (void)n_in; (void)out_size; (void)ws_size;
  const float* x        = (const float*)d_in[0];
  const float* wq       = (const float*)d_in[1];
  const float* bq       = (const float*)d_in[2];
  const float* wk       = (const float*)d_in[3];
  const float* bk       = (const float*)d_in[4];
  const float* wv       = (const float*)d_in[5];
  const float* bv       = (const float*)d_in[6];
  const float* ca_w1    = (const float*)d_in[7];
  const float* ca_w2    = (const float*)d_in[8];
  const float* conv_w   = (const float*)d_in[9];
  const float* bn_gamma = (const float*)d_in[10];
  const float* bn_beta  = (const float*)d_in[11];
  const float* bn_mean  = (const float*)d_in[12];
  const float* bn_var   = (const float*)d_in[13];
  float* out = (float*)d_out;

  float* ws = (float*)d_ws;
  float* pa      = ws;                          // [B][C][N] fp32
  bh16*  Vf      = (bh16*)(ws + 8388608);       // [B][64][8][512][8] bf16 (aliased by wpck later)
  fh16*  wpck    = (fh16*)(ws + 8388608);       // conv weights f16 (after attn)
  bh16*  Qb      = (bh16*)(ws + 12582912);      // [B*N][64] bf16
  bh16*  Kf      = (bh16*)(ws + 13107200);      // [B][64][8][64][8] bf16
  bh16*  xTb     = (bh16*)(ws + 13631488);      // [B][N][C] bf16 (aliased by pab later)
  fh16*  pab     = (fh16*)(ws + 13631488);      // [B][4356][512] f16 + pad
  bh16*  Wqk     = (bh16*)(ws + 17825792);      // [128][512] bf16
  bh16*  wvb     = (bh16*)(ws + 17858560);      // [512][512] bf16
  float* bias128 = ws + 17989632;
  float* avgv    = ws + 18100224;
  float* maxv    = ws + 18102272;
  float* scl     = ws + 18104320;

  wcast_k<<<dim3(1280, 1, 1), 256, 0, stream>>>(wq, wk, wv, bq, bk, Wqk, wvb, bias128);
  transpose_bf_k<<<dim3(NPIX / 32, CIN / 32, NB), dim3(32, 8, 1), 0, stream>>>(x, xTb, CIN, NPIX);
  qk_proj_k<<<dim3(256, 1, 1), 256, 0, stream>>>(xTb, Wqk, bias128, Qb, Kf);
  v_proj_k<<<dim3(16, 8, NB), 256, 0, stream>>>(xTb, wvb, bv, Vf);
  attn1p_k<<<dim3(2, 64, NB), 256, 0, stream>>>(Qb, Kf, Vf, x, pa);
  // xTb dead now: zero pab (incl. borders + tail pad)
  hipMemsetAsync(pab, 0, (size_t)(NB * PPIX * CIN + 16384) * sizeof(fh16), stream);
  pool2_k<<<dim3(512, 1, 1), 256, 0, stream>>>(pa, avgv, maxv);
  mlp2_k<<<dim3(NB, 1, 1), 256, 0, stream>>>(avgv, maxv, ca_w1, ca_w2, scl);
  pack_k<<<dim3(NPIX / 32, CIN / 64, NB), 256, 0, stream>>>(pa, scl, pab);
  wpack_k<<<dim3(576, 1, 1), 256, 0, stream>>>(conv_w, wpck);  // Vf dead now
  conv_mfma_k<<<dim3(16, 4, NB), 256, 0, stream>>>(pab, wpck, bn_gamma, bn_beta,
                                                   bn_mean, bn_var, out);
}